// Round 13
// baseline (14116.388 us; speedup 1.0000x reference)
//
#include <hip/hip_runtime.h>

#define BROWS 16384
#define HDIM  4096
#define H2    2048
#define EEXP  64
#define KSEL  12
#define NPAN  256   // HDIM / 16

typedef float f32x4 __attribute__((ext_vector_type(4)));

typedef __attribute__((address_space(1))) const unsigned int guint_t;
typedef __attribute__((address_space(3))) unsigned int luint_t;

__device__ __forceinline__ void gl16(const void* g, void* l){
  __builtin_amdgcn_global_load_lds((guint_t*)g, (luint_t*)l, 16, 0, 0);
}

// ---------- masked_w f32, replicating np: rw * (1/(1+exp(-m))) ----------
__global__ void k_mw32(const float* __restrict__ rw, const float* __restrict__ mk,
                       float* __restrict__ mw, int n){
  int i = blockIdx.x*blockDim.x + threadIdx.x;
  if (i < n){
    float m = mk[i];
    float u = (float)exp(-(double)m);
    mw[i] = rw[i] * (1.0f/(1.0f + u));
  }
}

// ---------- generic 32x32 tiled transpose: out[C][R] = in[R][C]^T ----------
__global__ __launch_bounds__(256)
void k_tr(const float* __restrict__ in, float* __restrict__ out, int R, int C){
  __shared__ float tile[32][33];
  const int t = threadIdx.x;
  const int cb = C >> 5;
  const int bx = blockIdx.x % cb, by = blockIdx.x / cb;
  const int lr = t >> 3, lc4 = (t & 7) * 4;
  f32x4 v = *(const f32x4*)(in + (size_t)(by*32 + lr)*C + bx*32 + lc4);
  tile[lr][lc4] = v[0]; tile[lr][lc4+1] = v[1];
  tile[lr][lc4+2] = v[2]; tile[lr][lc4+3] = v[3];
  __syncthreads();
  f32x4 o;
  o[0] = tile[lc4][lr]; o[1] = tile[lc4+1][lr];
  o[2] = tile[lc4+2][lr]; o[3] = tile[lc4+3][lr];
  *(f32x4*)(out + (size_t)(bx*32 + lr)*R + by*32 + lc4) = o;
}

// ---------- big h-GEMM: h[16384 x 2048] = relu(A . B^T + b1) ----------
// r12 structure + __launch_bounds__(256,2): VGPR cap 128 (live set ~105, no
// pinned operand arrays -> no spill), 4 waves/SIMD, 4 blocks/CU = 16 waves/CU.
// K-major LDS both operands; per kk 4 ds_read_b128 (broadcast-heavy, 2-way)
// + 64 fmaf. KP=16 double-buffered, ONE barrier/panel; B via global_load_lds,
// A global loads issued before compute, LDS-written after (T14).
// Bit-exact np-f32 chain: ONE f32 acc per output, fmaf over k ascending.
__global__ __launch_bounds__(256, 2)
void k_h(const float* __restrict__ A, const float* __restrict__ Btr,
         const float* __restrict__ bias, float* __restrict__ C)
{
  __shared__ float As[2][16][132];   // k-major, pad 132: staged writes 2-way
  __shared__ float Bs[2][16][128];   // k-major, gl_lds linear
  const int t = threadIdx.x, w = t>>6, l = t&63;
  const int ly = l>>3, lx = l&7;
  // XCD-chunked swizzle: 2048 wgs -> 256/XCD, same-mt neighbors share x panel
  const int bid = blockIdx.x;
  const int qq = bid >> 3;
  const int mt = (bid & 7)*16 + (qq >> 4), nt = qq & 15;
  const long m0 = (long)mt*128; const int n0 = nt*128;
  const int r0 = (w>>1)*64 + ly*8;
  const int c0 = (w&1)*64 + lx*8;

  float acc[8][8] = {};

  // A staging: thread t handles row t>>1, k-chunk (t&1)*8 (8 floats)
  const int arow = t>>1, kc = (t&1)*8;
  const float* ag = A + (m0 + arow)*(size_t)HDIM + kc;
  f32x4 av0, av1;
  auto loadAg = [&](int p){
    av0 = *(const f32x4*)(ag + p*16);
    av1 = *(const f32x4*)(ag + p*16 + 4);
  };
  auto writeA = [&](int buf){
    #pragma unroll
    for (int j=0;j<4;j++){
      As[buf][kc+j][arow]   = av0[j];   // banks = arow%32: 2-way, free
      As[buf][kc+4+j][arow] = av1[j];
    }
  };
  // B staging: per wave 2 gl_lds x 1024B (k-rows 4w..4w+3)
  const float* bg = Btr + n0 + (size_t)(l>>5)*H2 + (size_t)(l&31)*4;
  auto dmaB = [&](int p, int buf){
    #pragma unroll
    for (int i=0;i<2;i++)
      gl16(bg + (size_t)(p*16 + w*4 + 2*i)*H2, &Bs[buf][w*4 + 2*i][0]);
  };

  auto compute = [&](int buf){
    #pragma unroll
    for (int kk=0; kk<16; ++kk){
      f32x4 a0 = *(const f32x4*)&As[buf][kk][r0];
      f32x4 a1 = *(const f32x4*)&As[buf][kk][r0+4];
      f32x4 b0 = *(const f32x4*)&Bs[buf][kk][c0];
      f32x4 b1 = *(const f32x4*)&Bs[buf][kk][c0+4];
      #pragma unroll
      for (int i=0;i<4;i++)
        #pragma unroll
        for (int j=0;j<4;j++){
          acc[i][j]     = fmaf(a0[i], b0[j], acc[i][j]);
          acc[i][j+4]   = fmaf(a0[i], b1[j], acc[i][j+4]);
          acc[i+4][j]   = fmaf(a1[i], b0[j], acc[i+4][j]);
          acc[i+4][j+4] = fmaf(a1[i], b1[j], acc[i+4][j+4]);
        }
    }
  };

  loadAg(0); writeA(0); dmaB(0, 0);
  asm volatile("s_waitcnt vmcnt(0)" ::: "memory");
  __syncthreads();

  for (int p = 0; p < NPAN; ++p){
    const int buf = p & 1;
    if (p + 1 < NPAN){
      dmaB(p+1, buf^1);     // DMA overlaps compute
      loadAg(p+1);          // global A loads hide under compute (T14 issue)
    }
    compute(buf);
    if (p + 1 < NPAN) writeA(buf^1);   // T14 write-late
    asm volatile("s_waitcnt vmcnt(0)" ::: "memory");
    __syncthreads();
  }

  const float* bp = bias + n0 + c0;
  f32x4 bv0 = *(const f32x4*)bp, bv1 = *(const f32x4*)(bp+4);
  #pragma unroll
  for (int i=0;i<8;i++){
    const long row = m0 + r0 + i;
    f32x4 v0, v1;
    #pragma unroll
    for (int j=0;j<4;j++){
      v0[j] = fmaxf(acc[i][j]   + bv0[j], 0.f);
      v1[j] = fmaxf(acc[i][j+4] + bv1[j], 0.f);
    }
    *(f32x4*)&C[row*(long)H2 + n0 + c0]     = v0;
    *(f32x4*)&C[row*(long)H2 + n0 + c0 + 4] = v1;
  }
}

// ---------- small GEMM (rl, z): C = A . B^T, same bit-exact chain ----------
__global__ __launch_bounds__(256, 2)
void k_g32(const float* __restrict__ A, const float* __restrict__ B,
           float* __restrict__ C, int K, int ntiles,
           const float* __restrict__ bias, int relu)
{
  __shared__ float As[64][36];
  __shared__ float Bs[64][36];
  const int t = threadIdx.x;
  const int mt = blockIdx.x / ntiles, nt = blockIdx.x % ntiles;
  const long m0 = (long)mt*64; const int n0 = nt*64;
  const int ty = t>>4, tx = t&15;
  const int sr = t>>2, sc = (t&3)*8;
  float acc[4][4] = {{0.f,0.f,0.f,0.f},{0.f,0.f,0.f,0.f},
                     {0.f,0.f,0.f,0.f},{0.f,0.f,0.f,0.f}};
  const float* ap = A + (m0+sr)*(long)K + sc;
  const float* bp = B + ((size_t)(n0+sr))*K + sc;
  f32x4 a0,a1,b0,b1;
  auto gload = [&](int kb){
    a0 = *(const f32x4*)(ap + kb);
    a1 = *(const f32x4*)(ap + kb + 4);
    b0 = *(const f32x4*)(bp + kb);
    b1 = *(const f32x4*)(bp + kb + 4);
  };
  gload(0);
  for (int kb = 0; kb < K; kb += 32){
    __syncthreads();
    *(f32x4*)&As[sr][sc]   = a0; *(f32x4*)&As[sr][sc+4] = a1;
    *(f32x4*)&Bs[sr][sc]   = b0; *(f32x4*)&Bs[sr][sc+4] = b1;
    __syncthreads();
    if (kb + 32 < K) gload(kb + 32);
    #pragma unroll
    for (int kk = 0; kk < 32; kk += 4){
      f32x4 av[4], bv[4];
      #pragma unroll
      for (int i=0;i<4;i++) av[i] = *(const f32x4*)&As[ty+16*i][kk];
      #pragma unroll
      for (int j=0;j<4;j++) bv[j] = *(const f32x4*)&Bs[tx+16*j][kk];
      #pragma unroll
      for (int q=0;q<4;q++)
        #pragma unroll
        for (int i=0;i<4;i++)
          #pragma unroll
          for (int j=0;j<4;j++)
            acc[i][j] = fmaf(av[i][q], bv[j][q], acc[i][j]);
    }
  }
  #pragma unroll
  for (int i=0;i<4;i++){
    const long row = m0 + ty + 16*i;
    #pragma unroll
    for (int j=0;j<4;j++){
      const int col = n0 + tx + 16*j;
      float v = acc[i][j];
      if (bias) v = v + bias[col];
      if (relu) v = fmaxf(v, 0.f);
      C[row*(long)(ntiles*64) + col] = v;
    }
  }
}

// ---------- gates sigmoid + scaled logits ----------
__global__ void k_sig(const float* __restrict__ z, const float* __restrict__ rl,
                      const float* __restrict__ b2, float* __restrict__ s,
                      float* __restrict__ out0, int n){
  int i = blockIdx.x*blockDim.x + threadIdx.x;
  if (i < n){
    int e = i & (EEXP-1);
    float zz = z[i] + b2[e];
    float u = (float)exp(-(double)zz);
    float g = 1.0f/(1.0f + u);
    float sv = rl[i] * g;
    s[i] = sv;
    out0[i] = sv;
  }
}

// ---------- top-12 (stable), weights, softmax stats ----------
__global__ __launch_bounds__(256, 2)
void k_top(const float* __restrict__ s32, float* __restrict__ out,
           float* __restrict__ loadp, float* __restrict__ entp)
{
  __shared__ float P[256][65];
  __shared__ float entbuf[256];
  const int t = threadIdx.x;
  const long row = (long)blockIdx.x*256 + t;
  const float* srow = s32 + row*EEXP;

  float vals[KSEL]; int idxs[KSEL];
  float pv = INFINITY; int pi = -1;
  for (int kk=0; kk<KSEL; ++kk){
    float bv = -INFINITY; int bi = 0;
    for (int e=0; e<EEXP; ++e){
      float v = srow[e];
      bool after = (v < pv) || ((v == pv) && (e > pi));
      if (after && (v > bv)){ bv = v; bi = e; }
    }
    vals[kk] = bv; idxs[kk] = bi; pv = bv; pi = bi;
  }
  float* oi = out + (size_t)BROWS*EEXP;
  float* ow = oi + (size_t)BROWS*KSEL;
  const long obase = row*KSEL;
  {
    float ev[KSEL]; float sw = 0.f;
    #pragma unroll
    for (int kk=0; kk<KSEL; ++kk){ ev[kk] = expf(vals[kk]-vals[0]); sw += ev[kk]; }
    float inv = 1.f/sw;
    #pragma unroll
    for (int kk=0; kk<KSEL; ++kk){ oi[obase+kk] = (float)idxs[kk]; ow[obase+kk] = ev[kk]*inv; }
  }
  {
    float mx = vals[0];
    float sum = 0.f;
    for (int e=0; e<EEXP; ++e) sum += expf(srow[e] - mx);
    float isum = 1.f/sum, ent = 0.f;
    for (int e=0; e<EEXP; ++e){
      float p2 = expf(srow[e] - mx) * isum;
      ent -= p2 * logf(p2 + 1e-8f);
      P[t][e] = p2;
    }
    entbuf[t] = ent;
  }
  __syncthreads();
  if (t < 64){
    float s = 0.f;
    for (int r2=0; r2<256; ++r2) s += P[r2][t];
    loadp[blockIdx.x*64 + t] = s;
    float es = entbuf[t] + entbuf[t+64] + entbuf[t+128] + entbuf[t+192];
    for (int o=32; o; o>>=1) es += __shfl_down(es, o);
    if (t == 0) entp[blockIdx.x] = es;
  }
}

// ---------- finalize: load variance (ddof=1) + mean entropy ----------
__global__ void k_finalize(const float* __restrict__ loadp, const float* __restrict__ entp,
                           float* __restrict__ out){
  const int e = threadIdx.x;
  float s = 0.f;
  for (int b=0; b<64; ++b) s += loadp[b*64 + e];
  float load = s * (1.f/16384.f);
  float tsum = load;
  for (int o=32; o; o>>=1) tsum += __shfl_xor(tsum, o);
  float mean = tsum * (1.f/64.f);
  float d = load - mean;
  float v = d*d;
  for (int o=32; o; o>>=1) v += __shfl_xor(v, o);
  float var = v * (1.f/63.f);
  float es = entp[e];
  for (int o=32; o; o>>=1) es += __shfl_xor(es, o);
  if (e == 0){
    size_t off = (size_t)BROWS*EEXP + (size_t)BROWS*KSEL*2;
    out[off]     = var;
    out[off + 1] = es * (1.f/16384.f);
  }
}

extern "C" void kernel_launch(void* const* d_in, const int* in_sizes, int n_in,
                              void* d_out, int out_size, void* d_ws, size_t ws_size,
                              hipStream_t stream)
{
  const float* hidden = (const float*)d_in[0];
  const float* rw     = (const float*)d_in[1];
  const float* mk     = (const float*)d_in[2];
  const float* gw1    = (const float*)d_in[3];
  const float* gb1    = (const float*)d_in[4];
  const float* gw2    = (const float*)d_in[5];
  const float* gb2    = (const float*)d_in[6];
  float* out = (float*)d_out;

  unsigned char* ws = (unsigned char*)d_ws;
  size_t o = 0;
  float* mw  = (float*)(ws + o); o += (size_t)EEXP*HDIM*4;    // 1.05 MB
  float* Btr = (float*)(ws + o); o += (size_t)HDIM*H2*4;      // 33.55 MB
  float* h   = (float*)(ws + o); o += (size_t)BROWS*H2*4;     // 134.2 MB
  float* rl  = (float*)(ws + o); o += (size_t)BROWS*EEXP*4;   // 4.19 MB
  float* zb  = (float*)(ws + o); o += (size_t)BROWS*EEXP*4;   // 4.19 MB
  float* s32 = (float*)(ws + o); o += (size_t)BROWS*EEXP*4;   // 4.19 MB
  float* loadp = (float*)(ws + o); o += 64*64*4;
  float* entp  = (float*)(ws + o); o += 256;                  // ~182 MB total

  k_mw32<<<(EEXP*HDIM+255)/256, 256, 0, stream>>>(rw, mk, mw, EEXP*HDIM);
  // Btr[4096][2048] = gw1^T
  k_tr<<<(HDIM/32)*(H2/32), 256, 0, stream>>>(gw1, Btr, H2, HDIM);
  // h = relu(x @ w1^T + b1)
  k_h<<<(BROWS/128)*(H2/128), 256, 0, stream>>>(hidden, Btr, gb1, h);
  // rl = x @ mw^T
  k_g32<<<(BROWS/64)*1, 256, 0, stream>>>(hidden, mw, rl, HDIM, 1, nullptr, 0);
  // z = h @ w2^T
  k_g32<<<(BROWS/64)*1, 256, 0, stream>>>(h, gw2, zb, H2, 1, nullptr, 0);
  k_sig<<<(BROWS*EEXP+255)/256, 256, 0, stream>>>(zb, rl, gb2, s32, out, BROWS*EEXP);
  k_top<<<BROWS/256, 256, 0, stream>>>(s32, out, loadp, entp);
  k_finalize<<<1, 64, 0, stream>>>(loadp, entp, out);
}

// Round 14
// 3498.669 us; speedup vs baseline: 4.0348x; 4.0348x over previous
//
#include <hip/hip_runtime.h>

#define BROWS 16384
#define HDIM  4096
#define H2    2048
#define EEXP  64
#define KSEL  12

typedef float f32x4 __attribute__((ext_vector_type(4)));

// ---------- masked_w f32, replicating np: rw * (1/(1+exp(-m))) ----------
__global__ void k_mw32(const float* __restrict__ rw, const float* __restrict__ mk,
                       float* __restrict__ mw, int n){
  int i = blockIdx.x*blockDim.x + threadIdx.x;
  if (i < n){
    float m = mk[i];
    float u = (float)exp(-(double)m);      // ~= correctly-rounded f32 exp (np.exp)
    mw[i] = rw[i] * (1.0f/(1.0f + u));
  }
}

// ---------- big h-GEMM: C[16384 x 2048] = relu(A . B^T + b1) ----------
// Round-6 kernel (best measured: 3.53 ms, VGPR 68, no spill) + bijective
// XCD-chunked block swizzle: 2048 wgs = 8 xcd x 256; each XCD gets a
// contiguous 16mt x 16nt chunk so same-mt blocks share the A panel in L2.
// 128x128 tile, 256 thr, 8x8/thread, k-major LDS [32][132], global prefetch
// hidden under compute.
// Bit-exact np-f32 chain: per output ONE f32 acc, fmaf over k ascending.
__global__ __launch_bounds__(256, 3)
void k_h128(const float* __restrict__ A, const float* __restrict__ B,
            float* __restrict__ C, const float* __restrict__ bias)
{
  __shared__ float As[32][132];
  __shared__ float Bs[32][132];
  const int t = threadIdx.x;
  const int w = t>>6, l = t&63;
  const int wr = w>>1, wc = w&1;
  const int ly = l>>3, lx = l&7;
  // XCD-chunked swizzle (bijective: 2048 = 8*16*16)
  const int bid = blockIdx.x;
  const int qq = bid >> 3;
  const int mt = (bid & 7)*16 + (qq >> 4), nt = qq & 15;
  const long m0 = (long)mt*128; const int n0 = nt*128;
  const int myrow = wr*64 + ly*8;
  const int mycol = wc*64 + lx*8;
  const int sr = t>>1, sc = (t&1)*16;

  float acc[8][8] = {};
  const float* ap = A + (m0+sr)*(long)HDIM + sc;
  const float* bp = B + (size_t)(n0+sr)*HDIM + sc;

  f32x4 ar[4], br[4];
  auto gload = [&](int kb){
    #pragma unroll
    for (int u=0;u<4;u++){
      ar[u] = *(const f32x4*)(ap + kb + 4*u);
      br[u] = *(const f32x4*)(bp + kb + 4*u);
    }
  };
  gload(0);
  for (int kb = 0; kb < HDIM; kb += 32){
    __syncthreads();     // prior panel's LDS reads complete
    #pragma unroll
    for (int u=0;u<4;u++)
      #pragma unroll
      for (int v=0;v<4;v++){
        As[sc+4*u+v][sr] = ar[u][v];
        Bs[sc+4*u+v][sr] = br[u][v];
      }
    __syncthreads();
    if (kb + 32 < HDIM) gload(kb + 32);   // prefetch hides under compute
    #pragma unroll 8
    for (int kk = 0; kk < 32; ++kk){
      f32x4 a0 = *(const f32x4*)&As[kk][myrow];
      f32x4 a1 = *(const f32x4*)&As[kk][myrow+4];
      f32x4 b0 = *(const f32x4*)&Bs[kk][mycol];
      f32x4 b1 = *(const f32x4*)&Bs[kk][mycol+4];
      #pragma unroll
      for (int j=0;j<8;j++){
        float bj = (j<4) ? b0[j] : b1[j-4];
        #pragma unroll
        for (int i=0;i<8;i++){
          float ai = (i<4) ? a0[i] : a1[i-4];
          acc[i][j] = fmaf(ai, bj, acc[i][j]);
        }
      }
    }
  }
  #pragma unroll
  for (int i=0;i<8;i++){
    const long row = m0 + myrow + i;
    f32x4 v0, v1;
    #pragma unroll
    for (int j=0;j<4;j++){
      v0[j] = fmaxf(acc[i][j]   + bias[n0+mycol+j],   0.f);
      v1[j] = fmaxf(acc[i][j+4] + bias[n0+mycol+4+j], 0.f);
    }
    *(f32x4*)&C[row*(long)H2 + n0 + mycol]     = v0;
    *(f32x4*)&C[row*(long)H2 + n0 + mycol + 4] = v1;
  }
}

// ---------- small GEMM (rl, z): C = A . B^T, same bit-exact chain ----------
__global__ __launch_bounds__(256, 2)
void k_g32(const float* __restrict__ A, const float* __restrict__ B,
           float* __restrict__ C, int K, int ntiles,
           const float* __restrict__ bias, int relu)
{
  __shared__ float As[64][36];
  __shared__ float Bs[64][36];
  const int t = threadIdx.x;
  const int mt = blockIdx.x / ntiles, nt = blockIdx.x % ntiles;
  const long m0 = (long)mt*64; const int n0 = nt*64;
  const int ty = t>>4, tx = t&15;
  const int sr = t>>2, sc = (t&3)*8;
  float acc[4][4] = {{0.f,0.f,0.f,0.f},{0.f,0.f,0.f,0.f},
                     {0.f,0.f,0.f,0.f},{0.f,0.f,0.f,0.f}};
  const float* ap = A + (m0+sr)*(long)K + sc;
  const float* bp = B + ((size_t)(n0+sr))*K + sc;
  f32x4 a0,a1,b0,b1;
  auto gload = [&](int kb){
    a0 = *(const f32x4*)(ap + kb);
    a1 = *(const f32x4*)(ap + kb + 4);
    b0 = *(const f32x4*)(bp + kb);
    b1 = *(const f32x4*)(bp + kb + 4);
  };
  gload(0);
  for (int kb = 0; kb < K; kb += 32){
    __syncthreads();
    *(f32x4*)&As[sr][sc]   = a0; *(f32x4*)&As[sr][sc+4] = a1;
    *(f32x4*)&Bs[sr][sc]   = b0; *(f32x4*)&Bs[sr][sc+4] = b1;
    __syncthreads();
    if (kb + 32 < K) gload(kb + 32);
    #pragma unroll
    for (int kk = 0; kk < 32; kk += 4){
      f32x4 av[4], bv[4];
      #pragma unroll
      for (int i=0;i<4;i++) av[i] = *(const f32x4*)&As[ty+16*i][kk];
      #pragma unroll
      for (int j=0;j<4;j++) bv[j] = *(const f32x4*)&Bs[tx+16*j][kk];
      #pragma unroll
      for (int q=0;q<4;q++)
        #pragma unroll
        for (int i=0;i<4;i++)
          #pragma unroll
          for (int j=0;j<4;j++)
            acc[i][j] = fmaf(av[i][q], bv[j][q], acc[i][j]);
    }
  }
  #pragma unroll
  for (int i=0;i<4;i++){
    const long row = m0 + ty + 16*i;
    #pragma unroll
    for (int j=0;j<4;j++){
      const int col = n0 + tx + 16*j;
      float v = acc[i][j];
      if (bias) v = v + bias[col];
      if (relu) v = fmaxf(v, 0.f);
      C[row*(long)(ntiles*64) + col] = v;
    }
  }
}

// ---------- gates sigmoid + scaled logits: s = rl * (1/(1+exp(-(z+b2)))) ----------
__global__ void k_sig(const float* __restrict__ z, const float* __restrict__ rl,
                      const float* __restrict__ b2, float* __restrict__ s,
                      float* __restrict__ out0, int n){
  int i = blockIdx.x*blockDim.x + threadIdx.x;
  if (i < n){
    int e = i & (EEXP-1);
    float zz = z[i] + b2[e];
    float u = (float)exp(-(double)zz);
    float g = 1.0f/(1.0f + u);
    float sv = rl[i] * g;
    s[i] = sv;
    out0[i] = sv;
  }
}

// ---------- top-12 (f32, stable ties -> lower index), weights, softmax stats ----------
__global__ __launch_bounds__(256, 2)
void k_top(const float* __restrict__ s32, float* __restrict__ out,
           float* __restrict__ loadp, float* __restrict__ entp)
{
  __shared__ float P[256][65];
  __shared__ float entbuf[256];
  const int t = threadIdx.x;
  const long row = (long)blockIdx.x*256 + t;
  const float* srow = s32 + row*EEXP;

  float vals[KSEL]; int idxs[KSEL];
  float pv = INFINITY; int pi = -1;
  for (int kk=0; kk<KSEL; ++kk){
    float bv = -INFINITY; int bi = 0;
    for (int e=0; e<EEXP; ++e){
      float v = srow[e];
      bool after = (v < pv) || ((v == pv) && (e > pi));
      if (after && (v > bv)){ bv = v; bi = e; }
    }
    vals[kk] = bv; idxs[kk] = bi; pv = bv; pi = bi;
  }
  float* oi = out + (size_t)BROWS*EEXP;
  float* ow = oi + (size_t)BROWS*KSEL;
  const long obase = row*KSEL;
  {
    float ev[KSEL]; float sw = 0.f;
    #pragma unroll
    for (int kk=0; kk<KSEL; ++kk){ ev[kk] = expf(vals[kk]-vals[0]); sw += ev[kk]; }
    float inv = 1.f/sw;
    #pragma unroll
    for (int kk=0; kk<KSEL; ++kk){ oi[obase+kk] = (float)idxs[kk]; ow[obase+kk] = ev[kk]*inv; }
  }
  {
    float mx = vals[0];
    float sum = 0.f;
    for (int e=0; e<EEXP; ++e) sum += expf(srow[e] - mx);
    float isum = 1.f/sum, ent = 0.f;
    for (int e=0; e<EEXP; ++e){
      float p2 = expf(srow[e] - mx) * isum;
      ent -= p2 * logf(p2 + 1e-8f);
      P[t][e] = p2;
    }
    entbuf[t] = ent;
  }
  __syncthreads();
  if (t < 64){
    float s = 0.f;
    for (int r2=0; r2<256; ++r2) s += P[r2][t];
    loadp[blockIdx.x*64 + t] = s;
    float es = entbuf[t] + entbuf[t+64] + entbuf[t+128] + entbuf[t+192];
    for (int o=32; o; o>>=1) es += __shfl_down(es, o);
    if (t == 0) entp[blockIdx.x] = es;
  }
}

// ---------- finalize: load variance (ddof=1) + mean entropy ----------
__global__ void k_finalize(const float* __restrict__ loadp, const float* __restrict__ entp,
                           float* __restrict__ out){
  const int e = threadIdx.x; // 64 threads
  float s = 0.f;
  for (int b=0; b<64; ++b) s += loadp[b*64 + e];
  float load = s * (1.f/16384.f);
  float tsum = load;
  for (int o=32; o; o>>=1) tsum += __shfl_xor(tsum, o);
  float mean = tsum * (1.f/64.f);
  float d = load - mean;
  float v = d*d;
  for (int o=32; o; o>>=1) v += __shfl_xor(v, o);
  float var = v * (1.f/63.f);
  float es = entp[e];
  for (int o=32; o; o>>=1) es += __shfl_xor(es, o);
  if (e == 0){
    size_t off = (size_t)BROWS*EEXP + (size_t)BROWS*KSEL*2;
    out[off]     = var;
    out[off + 1] = es * (1.f/16384.f);
  }
}

extern "C" void kernel_launch(void* const* d_in, const int* in_sizes, int n_in,
                              void* d_out, int out_size, void* d_ws, size_t ws_size,
                              hipStream_t stream)
{
  const float* hidden = (const float*)d_in[0];
  const float* rw     = (const float*)d_in[1];
  const float* mk     = (const float*)d_in[2];
  const float* gw1    = (const float*)d_in[3];
  const float* gb1    = (const float*)d_in[4];
  const float* gw2    = (const float*)d_in[5];
  const float* gb2    = (const float*)d_in[6];
  float* out = (float*)d_out;

  unsigned char* ws = (unsigned char*)d_ws;
  size_t o = 0;
  float* mw  = (float*)(ws + o); o += (size_t)EEXP*HDIM*4;    // 1.05 MB
  float* h   = (float*)(ws + o); o += (size_t)BROWS*H2*4;     // 134.2 MB
  float* rl  = (float*)(ws + o); o += (size_t)BROWS*EEXP*4;   // 4.19 MB
  float* zb  = (float*)(ws + o); o += (size_t)BROWS*EEXP*4;   // 4.19 MB
  float* s32 = (float*)(ws + o); o += (size_t)BROWS*EEXP*4;   // 4.19 MB
  float* loadp = (float*)(ws + o); o += 64*64*4;
  float* entp  = (float*)(ws + o); o += 256;                  // ~148 MB total

  // masked router weights (f32, np-rounding)
  k_mw32<<<(EEXP*HDIM+255)/256, 256, 0, stream>>>(rw, mk, mw, EEXP*HDIM);
  // h = relu(x @ w1^T + b1)  [16384,2048]  — 128x128 tiles, XCD-swizzled
  k_h128<<<(BROWS/128)*(H2/128), 256, 0, stream>>>(hidden, gw1, h, gb1);
  // rl = x @ mw^T  [16384,64]
  k_g32<<<(BROWS/64)*1, 256, 0, stream>>>(hidden, mw, rl, HDIM, 1, nullptr, 0);
  // z = h @ w2^T  [16384,64]
  k_g32<<<(BROWS/64)*1, 256, 0, stream>>>(h, gw2, zb, H2, 1, nullptr, 0);
  // gates + scaled logits
  k_sig<<<(BROWS*EEXP+255)/256, 256, 0, stream>>>(zb, rl, gb2, s32, out, BROWS*EEXP);
  // top-k + stats
  k_top<<<BROWS/256, 256, 0, stream>>>(s32, out, loadp, entp);
  k_finalize<<<1, 64, 0, stream>>>(loadp, entp, out);
}